// Round 1
// baseline (1571.167 us; speedup 1.0000x reference)
//
#include <hip/hip_runtime.h>
#include <hip/hip_bf16.h>
#include <stdint.h>

#define IN_F   4096
#define OUT_F  11008
#define M_TOT  8192
#define ZCOLS  (OUT_F / 8)      // 1376
#define KK_ROWS (IN_F / 8)      // 512

#define BM 128
#define BN 128
#define BK 64

typedef __attribute__((ext_vector_type(8))) short  bf16x8;
typedef __attribute__((ext_vector_type(4))) float  f32x4;

__device__ __forceinline__ ushort f2bf(float f) {
    __hip_bfloat16 h = __float2bfloat16(f);   // RTNE
    return *reinterpret_cast<ushort*>(&h);
}

// ---------------- Phase 1: x fp32 -> bf16 ----------------
__global__ void convert_x(const float4* __restrict__ x, ushort4* __restrict__ xb) {
    int t = blockIdx.x * 256 + threadIdx.x;        // 8,388,608 threads total
    float4 v = x[t];
    xb[t] = make_ushort4(f2bf(v.x), f2bf(v.y), f2bf(v.z), f2bf(v.w));
}

// ---------------- Phase 2: dequant -> Wt [N][K] bf16 ----------------
// thread t: n = t>>9 (0..11007), kk = t&511 (0..511); one int32 of qweight ->
// 8 consecutive k values of column n -> one 16B chunk of row n of Wt.
__global__ void dequant_w(const int* __restrict__ qw, const int* __restrict__ qz,
                          const float* __restrict__ sc, ushort* __restrict__ wt) {
    int t  = blockIdx.x * 256 + threadIdx.x;       // 5,636,096 threads total
    int n  = t >> 9;
    int kk = t & 511;
    int g  = kk >> 4;                               // group = (kk*8)/128
    int w  = qw[kk * OUT_F + n];
    int z  = (qz[g * ZCOLS + (n >> 3)] >> ((n & 7) * 4)) & 15;
    float s = sc[g * OUT_F + n];
    ushort r[8];
#pragma unroll
    for (int i = 0; i < 8; ++i) {
        int q = (w >> (4 * i)) & 15;
        r[i] = f2bf((float)(q - z) * s);
    }
    ushort4* dst = (ushort4*)(wt + (size_t)n * IN_F + kk * 8);
    dst[0] = make_ushort4(r[0], r[1], r[2], r[3]);
    dst[1] = make_ushort4(r[4], r[5], r[6], r[7]);
}

// ---------------- Phase 3: C = A @ Bt^T + bias ----------------
// A  [M, K] bf16 row-major (K contiguous)
// Bt [N, K] bf16 row-major (K contiguous) == W^T
// C  [M, N] fp32
__global__ __launch_bounds__(256)
void gemm_bf16(const ushort* __restrict__ A, const ushort* __restrict__ Bt,
               const float* __restrict__ bias, float* __restrict__ C) {
    __shared__ ushort As[BM * BK];   // [m][k], 16 KB
    __shared__ ushort Bs[BN * BK];   // [n][k], 16 KB

    const int tid  = threadIdx.x;
    const int bn0  = blockIdx.x * BN;
    const int bm0  = blockIdx.y * BM;
    const int wave = tid >> 6;
    const int lane = tid & 63;
    const int wm   = (wave >> 1) * 64;   // wave row offset in C-tile
    const int wn   = (wave & 1) * 64;    // wave col offset
    const int lm   = lane & 15;
    const int lq   = lane >> 4;

    // staging: thread t loads 16B = 8 bf16 along K; covers 32 rows/pass, 4 passes
    const int srow = tid >> 3;           // 0..31
    const int scol = (tid & 7) * 8;      // 0..56
    const ushort* gA = A  + (size_t)(bm0 + srow) * IN_F + scol;
    const ushort* gB = Bt + (size_t)(bn0 + srow) * IN_F + scol;
    // wave-uniform LDS base (global_load_lds writes base + lane*16B)
    ushort* lA = As + wave * 512;        // elements (wave*1024 bytes)
    ushort* lB = Bs + wave * 512;

    f32x4 acc[4][4] = {};

    for (int kt = 0; kt < IN_F; kt += BK) {
#pragma unroll
        for (int p = 0; p < 4; ++p) {
            __builtin_amdgcn_global_load_lds(
                (const __attribute__((address_space(1))) void*)(gA + (size_t)p * 32 * IN_F + kt),
                (__attribute__((address_space(3))) void*)(lA + p * 32 * BK),
                16, 0, 0);
            __builtin_amdgcn_global_load_lds(
                (const __attribute__((address_space(1))) void*)(gB + (size_t)p * 32 * IN_F + kt),
                (__attribute__((address_space(3))) void*)(lB + p * 32 * BK),
                16, 0, 0);
        }
        __syncthreads();   // drains vmcnt before any LDS read

#pragma unroll
        for (int ks = 0; ks < 2; ++ks) {
            bf16x8 af[4], bfv[4];
#pragma unroll
            for (int i = 0; i < 4; ++i) {
                af[i]  = *(const bf16x8*)&As[(wm + i * 16 + lm) * BK + ks * 32 + lq * 8];
                bfv[i] = *(const bf16x8*)&Bs[(wn + i * 16 + lm) * BK + ks * 32 + lq * 8];
            }
#pragma unroll
            for (int i = 0; i < 4; ++i)
#pragma unroll
                for (int j = 0; j < 4; ++j)
                    acc[i][j] = __builtin_amdgcn_mfma_f32_16x16x32_bf16(
                        af[i], bfv[j], acc[i][j], 0, 0, 0);
        }
        __syncthreads();   // protect LDS from next iteration's staging
    }

    // epilogue: C row = bm0+wm+i*16+lq*4+r, col = bn0+wn+j*16+lm
    const int cm0 = bm0 + wm + lq * 4;
    const int cn0 = bn0 + wn + lm;
#pragma unroll
    for (int j = 0; j < 4; ++j) {
        const int n = cn0 + j * 16;
        const float bv = bias[n];
#pragma unroll
        for (int i = 0; i < 4; ++i) {
            float* out = C + (size_t)(cm0 + i * 16) * OUT_F + n;
#pragma unroll
            for (int r = 0; r < 4; ++r)
                out[(size_t)r * OUT_F] = acc[i][j][r] + bv;
        }
    }
}

extern "C" void kernel_launch(void* const* d_in, const int* in_sizes, int n_in,
                              void* d_out, int out_size, void* d_ws, size_t ws_size,
                              hipStream_t stream) {
    const float* x       = (const float*)d_in[0];  // [4,2048,4096]
    const float* scales  = (const float*)d_in[1];  // [32,11008]
    const float* bias    = (const float*)d_in[2];  // [11008]
    const int*   qweight = (const int*)d_in[3];    // [512,11008]
    const int*   qzeros  = (const int*)d_in[4];    // [32,1376]
    float* out = (float*)d_out;                    // [8192,11008]

    // workspace layout: xb (67,108,864 B) | wt (90,177,536 B)  => 157,286,400 B
    ushort* xb = (ushort*)d_ws;
    ushort* wt = (ushort*)((char*)d_ws + (size_t)M_TOT * IN_F * 2);

    convert_x<<<(M_TOT * IN_F / 4) / 256, 256, 0, stream>>>((const float4*)x, (ushort4*)xb);
    dequant_w<<<(OUT_F * KK_ROWS) / 256, 256, 0, stream>>>(qweight, qzeros, scales, wt);
    gemm_bf16<<<dim3(OUT_F / BN, M_TOT / BM), 256, 0, stream>>>(xb, wt, bias, out);
}